// Round 3
// baseline (2402834.766 us; speedup 1.0000x reference)
//
#include <hip/hip_runtime.h>
#include <stdint.h>

typedef _Float16 f16;
typedef f16 f16x2 __attribute__((ext_vector_type(2)));

#define T_LEN 32768
#define HID   512
#define IN_D  1024
#define OUT_D 128
#define NT    256          // scan threads: 4 waves, 1 per SIMD
#define NRW   384          // per-thread W_ode dwords in VGPRs (p < 48)
#define NLD   (512 - NRW)  // 128 dwords via LDS
#define NL4   (NLD / 4)    // 32 b128 chunks per thread
#define NR4   (NRW / 4)    // 96 b128 chunks in regs

__device__ __forceinline__ float dot2f(uint32_t w, uint32_t v, float acc) {
    return __builtin_amdgcn_fdot2(__builtin_bit_cast(f16x2, w),
                                  __builtin_bit_cast(f16x2, v), acc, false);
}
__device__ __forceinline__ float fast_tanh(float z) {
    float e = __expf(2.f * z);
    return 1.f - 2.f * __builtin_amdgcn_rcpf(e + 1.f);
}
__device__ __forceinline__ uint32_t pick(uint4 v, int j) {
    return j == 0 ? v.x : j == 1 ? v.y : j == 2 ? v.z : v.w;
}

// ---------------------------------------------------------------------------
// K0: pack W_ode / W_h (fp32 -> f16x2 dwords) in the scan kernel's layout.
// thread q owns rows 2q, 2q+1. Per-thread dword index d = p*8 + ch,
// ch = c*2 + r (c = k-chunk 0..3, r = row parity), covering
// W[2q+r][c*128 + 2p .. +1],  p in [0,64).
// Global placement (dwords): prep[(d>>2)*1024 + q*4 + (d&3)]  -> as uint4:
// prep4[(d>>2)*256 + q]  (lane-contiguous 16B, perfectly coalesced).
// ---------------------------------------------------------------------------
__global__ __launch_bounds__(NT) void k_prep(const float* __restrict__ W_ode,
                                             const float* __restrict__ W_h,
                                             uint32_t* __restrict__ ode_prep,
                                             uint32_t* __restrict__ wh_prep) {
    const int q = threadIdx.x;
    const float* W = blockIdx.x ? W_h : W_ode;
    uint32_t* dst  = blockIdx.x ? wh_prep : ode_prep;
    for (int d = 0; d < 512; ++d) {
        int p = d >> 3, ch = d & 7, c = ch >> 1, r = ch & 1;
        int row = 2 * q + r;
        int col = c * 128 + 2 * p;
        f16x2 pk;
        pk[0] = (f16)W[row * HID + col];
        pk[1] = (f16)W[row * HID + col + 1];
        dst[(d >> 2) * 1024 + q * 4 + (d & 3)] = __builtin_bit_cast(uint32_t, pk);
    }
}

// ---------------------------------------------------------------------------
// K1: pre[i][j] = W_in @ x_i + b_in + b_h   (fp32 tiled GEMM) — unchanged.
// ---------------------------------------------------------------------------
__global__ __launch_bounds__(512) void k_pre(const float* __restrict__ x,
                                             const float* __restrict__ W_in,
                                             const float* __restrict__ b_in,
                                             const float* __restrict__ b_h,
                                             float* __restrict__ pre32,
                                             uint16_t* __restrict__ pre16,
                                             int preF32) {
    __shared__ float xs[64][34];
    __shared__ float wsh[256][34];
    const int t  = threadIdx.x;
    const int i0 = (blockIdx.x >> 1) * 64;
    const int j0 = (blockIdx.x & 1) * 256;
    const int ti = t >> 5, tj = t & 31;

    float acc[4][8];
#pragma unroll
    for (int a = 0; a < 4; ++a)
#pragma unroll
        for (int b = 0; b < 8; ++b) acc[a][b] = 0.f;

    for (int kb = 0; kb < 32; ++kb) {
        __syncthreads();
        {   // x tile: 64 x 32
            int r = t >> 3, c = (t & 7) * 4;
            float4 v = *(const float4*)&x[(size_t)(i0 + r) * IN_D + kb * 32 + c];
            xs[r][c] = v.x; xs[r][c + 1] = v.y; xs[r][c + 2] = v.z; xs[r][c + 3] = v.w;
        }
        {   // W tile: 256 x 32
            int jr = t >> 1, c0 = (t & 1) * 16;
#pragma unroll
            for (int qd = 0; qd < 4; ++qd) {
                float4 v = *(const float4*)&W_in[(size_t)(j0 + jr) * IN_D + kb * 32 + c0 + qd * 4];
                wsh[jr][c0 + qd * 4]     = v.x; wsh[jr][c0 + qd * 4 + 1] = v.y;
                wsh[jr][c0 + qd * 4 + 2] = v.z; wsh[jr][c0 + qd * 4 + 3] = v.w;
            }
        }
        __syncthreads();
#pragma unroll 4
        for (int k = 0; k < 32; ++k) {
            float xv[4], wv[8];
#pragma unroll
            for (int ii = 0; ii < 4; ++ii) xv[ii] = xs[ti * 4 + ii][k];
#pragma unroll
            for (int jj = 0; jj < 8; ++jj) wv[jj] = wsh[tj + 32 * jj][k];
#pragma unroll
            for (int ii = 0; ii < 4; ++ii)
#pragma unroll
                for (int jj = 0; jj < 8; ++jj)
                    acc[ii][jj] = fmaf(xv[ii], wv[jj], acc[ii][jj]);
        }
    }
#pragma unroll
    for (int ii = 0; ii < 4; ++ii)
#pragma unroll
        for (int jj = 0; jj < 8; ++jj) {
            int ig = i0 + ti * 4 + ii, jg = j0 + tj + 32 * jj;
            float r = acc[ii][jj] + b_in[jg] + b_h[jg];
            if (preF32) pre32[(size_t)ig * HID + jg] = r;
            else        pre16[(size_t)ig * HID + jg] = __builtin_bit_cast(uint16_t, (f16)r);
        }
}

// ---------------------------------------------------------------------------
// K2: sequential scan. 256 threads (4 waves, 1/SIMD, 512-VGPR budget).
// Thread q owns rows 2q,2q+1 end-to-end: no cross-lane reduce at all.
// ---------------------------------------------------------------------------
__global__ __launch_bounds__(NT, 1) void k_scan(
    const uint32_t* __restrict__ ode_prep, const uint32_t* __restrict__ wh_prep,
    const float* __restrict__ pre32, const uint16_t* __restrict__ pre16, int preF32,
    const float* __restrict__ tarr, const float* __restrict__ b_ode,
    const float* __restrict__ W_dec, const float* __restrict__ b_dec,
    float* __restrict__ out)
{
    __shared__ uint4    wlds4[NL4 * NT];   // 128 KB: W_ode tail, lane-contiguous
    __shared__ uint32_t vbuf[2][NT];       // packed f16x2 v-vector, double-buffered
    __shared__ float    hbuf[HID];

    const int q = threadIdx.x;
    const uint4* ode4 = (const uint4*)ode_prep;
    const uint4* wh4  = (const uint4*)wh_prep;

    uint32_t wreg[NRW];
#pragma unroll
    for (int D4 = 0; D4 < NR4; ++D4) {
        uint4 w = ode4[D4 * NT + q];
        wreg[4 * D4]     = w.x; wreg[4 * D4 + 1] = w.y;
        wreg[4 * D4 + 2] = w.z; wreg[4 * D4 + 3] = w.w;
    }
#pragma unroll
    for (int L4 = 0; L4 < NL4; ++L4)
        wlds4[L4 * NT + q] = ode4[(NR4 + L4) * NT + q];

    const float2 bo = *(const float2*)&b_ode[2 * q];
    __syncthreads();

    int cur = 1;
    auto push2 = [&](float a, float b) {
        int nxt = cur ^ 1;
        uint32_t ua = (uint32_t)__builtin_bit_cast(uint16_t, (f16)a);
        uint32_t ub = (uint32_t)__builtin_bit_cast(uint16_t, (f16)b);
        vbuf[nxt][q] = ua | (ub << 16);
        __syncthreads();
        cur = nxt;
    };

    float z0, z1;

    // z = W_ode * v  (rows 2q, 2q+1); W: wreg for p<48, LDS stream for p>=48
    auto mv_ode = [&]() {
        float acc[8] = {0.f, 0.f, 0.f, 0.f, 0.f, 0.f, 0.f, 0.f};
        const uint4* vb4 = (const uint4*)&vbuf[cur][0];
        uint4 wl[2][8];
#pragma unroll
        for (int p4 = 0; p4 < 16; ++p4) {
            uint4 v0 = vb4[p4], v1 = vb4[16 + p4], v2 = vb4[32 + p4], v3 = vb4[48 + p4];
            if (p4 >= 11 && p4 <= 14) {      // prefetch LDS-W one block ahead
                const int b = p4 - 11;       // chunk-block 0..3 for use at p4+1
#pragma unroll
                for (int j = 0; j < 8; ++j)
                    wl[b & 1][j] = wlds4[(b * 8 + j) * NT + q];
            }
#pragma unroll
            for (int pp = 0; pp < 4; ++pp) {
                const int p = p4 * 4 + pp;
                const uint32_t vd0 = pick(v0, pp), vd1 = pick(v1, pp);
                const uint32_t vd2 = pick(v2, pp), vd3 = pick(v3, pp);
#pragma unroll
                for (int ch = 0; ch < 8; ++ch) {
                    const int d = p * 8 + ch;
                    uint32_t w;
                    if (d < NRW) {
                        w = wreg[d];
                    } else {
                        const int L = d - NRW;
                        w = pick(wl[(L >> 5) & 1][(L >> 2) & 7], L & 3);
                    }
                    const uint32_t vv = (ch < 2) ? vd0 : (ch < 4) ? vd1
                                      : (ch < 6) ? vd2 : vd3;
                    acc[ch] = dot2f(w, vv, acc[ch]);
                }
            }
        }
        z0 = acc[0] + acc[2] + acc[4] + acc[6];
        z1 = acc[1] + acc[3] + acc[5] + acc[7];
    };

    // z = W_h * v ; W_h streamed from L2, double-buffered 8x b128 per block
    auto mv_wh = [&]() {
        float acc[8] = {0.f, 0.f, 0.f, 0.f, 0.f, 0.f, 0.f, 0.f};
        const uint4* vb4 = (const uint4*)&vbuf[cur][0];
        uint4 wh[2][8];
#pragma unroll
        for (int j = 0; j < 8; ++j) wh[0][j] = wh4[j * NT + q];
#pragma unroll
        for (int p4 = 0; p4 < 16; ++p4) {
            uint4 v0 = vb4[p4], v1 = vb4[16 + p4], v2 = vb4[32 + p4], v3 = vb4[48 + p4];
            if (p4 < 15) {
#pragma unroll
                for (int j = 0; j < 8; ++j)
                    wh[(p4 + 1) & 1][j] = wh4[((p4 + 1) * 8 + j) * NT + q];
            }
#pragma unroll
            for (int pp = 0; pp < 4; ++pp) {
                const int p = p4 * 4 + pp;
                const uint32_t vd0 = pick(v0, pp), vd1 = pick(v1, pp);
                const uint32_t vd2 = pick(v2, pp), vd3 = pick(v3, pp);
#pragma unroll
                for (int ch = 0; ch < 8; ++ch) {
                    const int d = p * 8 + ch;
                    const uint32_t w = pick(wh[p4 & 1][(d >> 2) & 7], d & 3);
                    const uint32_t vv = (ch < 2) ? vd0 : (ch < 4) ? vd1
                                      : (ch < 6) ? vd2 : vd3;
                    acc[ch] = dot2f(w, vv, acc[ch]);
                }
            }
        }
        z0 = acc[0] + acc[2] + acc[4] + acc[6];
        z1 = acc[1] + acc[3] + acc[5] + acc[7];
    };

    // h0 = tanh(pre[0])
    float h0, h1;
    {
        float a0, a1;
        if (preF32) { float2 t2 = *(const float2*)&pre32[2 * q]; a0 = t2.x; a1 = t2.y; }
        else {
            uint32_t u = *(const uint32_t*)&pre16[2 * q];
            f16x2 f = __builtin_bit_cast(f16x2, u); a0 = (float)f[0]; a1 = (float)f[1];
        }
        h0 = fast_tanh(a0); h1 = fast_tanh(a1);
    }
    push2(h0, h1);
    float tprev = tarr[0];

#pragma unroll 1
    for (int i = 1; i < T_LEN; ++i) {
        float tc  = tarr[i];
        float dtt = tc - tprev; tprev = tc;
        float dt  = 0.25f * dtt;            // N_SUB = 4
        float hdt = 0.5f * dt;
        float sixth = dt * (1.f / 6.f);
        float p0, p1;
        if (preF32) {
            float2 t2 = *(const float2*)&pre32[(size_t)i * HID + 2 * q];
            p0 = t2.x; p1 = t2.y;
        } else {
            uint32_t u = *(const uint32_t*)&pre16[(size_t)i * HID + 2 * q];
            f16x2 f = __builtin_bit_cast(f16x2, u); p0 = (float)f[0]; p1 = (float)f[1];
        }
        // N_SUB = 4 RK4 substeps, each = 4 dependent mv_ode evals
#pragma unroll 1
        for (int sub = 0; sub < 4; ++sub) {
            float ks0 = 0.f, ks1 = 0.f;
#pragma unroll 1
            for (int s = 0; s < 4; ++s) {
                mv_ode();
                float k0  = fast_tanh(z0 + bo.x);
                float k1v = fast_tanh(z1 + bo.y);
                float wk = (s == 1 || s == 2) ? 2.f : 1.f;
                ks0 = fmaf(wk, k0, ks0); ks1 = fmaf(wk, k1v, ks1);
                float n0, n1;
                if (s == 3) {
                    h0 = fmaf(sixth, ks0, h0);
                    h1 = fmaf(sixth, ks1, h1);
                    n0 = h0; n1 = h1;       // v for next substep (or W_h matvec)
                } else {
                    float a = (s == 2) ? dt : hdt;
                    n0 = fmaf(a, k0, h0); n1 = fmaf(a, k1v, h1);
                }
                push2(n0, n1);
            }
        }
        mv_wh();
        h0 = fast_tanh(p0 + z0);
        h1 = fast_tanh(p1 + z1);
        push2(h0, h1);
    }

    // decode: out = W_dec @ h + b_dec
    hbuf[2 * q] = h0; hbuf[2 * q + 1] = h1;
    __syncthreads();
    if (q < OUT_D) {
        float a = b_dec[q];
#pragma unroll 4
        for (int r4 = 0; r4 < 128; ++r4) {
            float4 w = *(const float4*)&W_dec[q * HID + r4 * 4];
            a = fmaf(w.x, hbuf[r4 * 4],     a);
            a = fmaf(w.y, hbuf[r4 * 4 + 1], a);
            a = fmaf(w.z, hbuf[r4 * 4 + 2], a);
            a = fmaf(w.w, hbuf[r4 * 4 + 3], a);
        }
        out[q] = a;
    }
}

// ---------------------------------------------------------------------------
extern "C" void kernel_launch(void* const* d_in, const int* in_sizes, int n_in,
                              void* d_out, int out_size, void* d_ws, size_t ws_size,
                              hipStream_t stream) {
    const float* tarr  = (const float*)d_in[0];
    const float* x     = (const float*)d_in[1];
    const float* W_in  = (const float*)d_in[2];
    const float* b_in  = (const float*)d_in[3];
    const float* W_h   = (const float*)d_in[4];
    const float* b_h   = (const float*)d_in[5];
    const float* W_ode = (const float*)d_in[6];
    const float* b_ode = (const float*)d_in[7];
    const float* W_dec = (const float*)d_in[8];
    const float* b_dec = (const float*)d_in[9];
    float* out = (float*)d_out;

    uint8_t*  ws       = (uint8_t*)d_ws;
    uint32_t* ode_prep = (uint32_t*)(ws);                  // 512 KB
    uint32_t* wh_prep  = (uint32_t*)(ws + (512u << 10));   // 512 KB
    void*     pre      = (void*)(ws + (1u << 20));         // 64 MB f32 or 32 MB f16

    size_t need32 = (1u << 20) + (size_t)T_LEN * HID * 4 + 4096;
    int preF32 = (ws_size >= need32) ? 1 : 0;

    hipLaunchKernelGGL(k_prep, dim3(2), dim3(NT), 0, stream, W_ode, W_h, ode_prep, wh_prep);
    hipLaunchKernelGGL(k_pre,  dim3(1024), dim3(512), 0, stream, x, W_in, b_in, b_h,
                       (float*)pre, (uint16_t*)pre, preF32);
    hipLaunchKernelGGL(k_scan, dim3(1), dim3(NT), 0, stream, ode_prep, wh_prep,
                       (const float*)pre, (const uint16_t*)pre, preF32,
                       tarr, b_ode, W_dec, b_dec, out);
}

// Round 4
// 1180157.910 us; speedup vs baseline: 2.0360x; 2.0360x over previous
//
#include <hip/hip_runtime.h>
#include <stdint.h>

typedef _Float16 f16;
typedef f16 f16x2 __attribute__((ext_vector_type(2)));

#define T_LEN 32768
#define HID   512
#define IN_D  1024
#define OUT_D 128
#define NT    512          // scan threads: 8 waves, 2 per SIMD, 256-VGPR cap
// Per-thread W_ode: 256 dwords (8 rows x 64 k as f16x2).
// dd = rl*32 + c8*4 + mm  (rl 0..7 row-local, c8 0..7 k-chunk, mm 0..3)
// dd <176  -> VGPR (rl 0..4 all; rl5 c8 0..3)
// 176..247 -> LDS chunk (dd-176)>>2 in [0,18)
// 248..255 -> global stream (uint4 j=62,63; 16KB region, L1-resident)

__device__ __forceinline__ float dot2f(uint32_t w, uint32_t v, float acc) {
    return __builtin_amdgcn_fdot2(__builtin_bit_cast(f16x2, w),
                                  __builtin_bit_cast(f16x2, v), acc, false);
}
__device__ __forceinline__ float fast_tanh(float z) {
    float e = __expf(2.f * z);
    return 1.f - 2.f * __builtin_amdgcn_rcpf(e + 1.f);
}
__device__ __forceinline__ uint32_t pick(uint4 v, int j) {
    return j == 0 ? v.x : j == 1 ? v.y : j == 2 ? v.z : v.w;
}

// ---------------------------------------------------------------------------
// K0: pack W (fp32) -> f16x2 dwords, layout dst4[j*512 + t], j in [0,64),
// element (j,mm): dd=4j+mm -> rl=dd>>5, c8=(dd>>2)&7;
// row=(t>>3)*8+rl, k0=(t&7)*64+c8*8+mm*2 -> pack(W[row][k0], W[row][k0+1]).
// ---------------------------------------------------------------------------
__global__ __launch_bounds__(NT) void k_prep(const float* __restrict__ W_ode,
                                             const float* __restrict__ W_h,
                                             uint32_t* __restrict__ ode_prep,
                                             uint32_t* __restrict__ wh_prep) {
    const int t = threadIdx.x;
    const float* W = blockIdx.x ? W_h : W_ode;
    uint4* dst = (uint4*)(blockIdx.x ? wh_prep : ode_prep);
    const int rg = t >> 3, kg = t & 7;
    for (int j = 0; j < 64; ++j) {
        uint32_t c[4];
#pragma unroll
        for (int mm = 0; mm < 4; ++mm) {
            int dd = 4 * j + mm, rl = dd >> 5, c8 = (dd >> 2) & 7;
            int row = rg * 8 + rl;
            int k0  = kg * 64 + c8 * 8 + mm * 2;
            f16x2 pk;
            pk[0] = (f16)W[row * HID + k0];
            pk[1] = (f16)W[row * HID + k0 + 1];
            c[mm] = __builtin_bit_cast(uint32_t, pk);
        }
        dst[j * NT + t] = uint4{c[0], c[1], c[2], c[3]};
    }
}

// ---------------------------------------------------------------------------
// K1: pre[i][j] = W_in @ x_i + b_in + b_h   (fp32 tiled GEMM) — unchanged.
// ---------------------------------------------------------------------------
__global__ __launch_bounds__(512) void k_pre(const float* __restrict__ x,
                                             const float* __restrict__ W_in,
                                             const float* __restrict__ b_in,
                                             const float* __restrict__ b_h,
                                             float* __restrict__ pre32,
                                             uint16_t* __restrict__ pre16,
                                             int preF32) {
    __shared__ float xs[64][34];
    __shared__ float wsh[256][34];
    const int t  = threadIdx.x;
    const int i0 = (blockIdx.x >> 1) * 64;
    const int j0 = (blockIdx.x & 1) * 256;
    const int ti = t >> 5, tj = t & 31;

    float acc[4][8];
#pragma unroll
    for (int a = 0; a < 4; ++a)
#pragma unroll
        for (int b = 0; b < 8; ++b) acc[a][b] = 0.f;

    for (int kb = 0; kb < 32; ++kb) {
        __syncthreads();
        {   // x tile: 64 x 32
            int r = t >> 3, c = (t & 7) * 4;
            float4 v = *(const float4*)&x[(size_t)(i0 + r) * IN_D + kb * 32 + c];
            xs[r][c] = v.x; xs[r][c + 1] = v.y; xs[r][c + 2] = v.z; xs[r][c + 3] = v.w;
        }
        {   // W tile: 256 x 32
            int jr = t >> 1, c0 = (t & 1) * 16;
#pragma unroll
            for (int qd = 0; qd < 4; ++qd) {
                float4 v = *(const float4*)&W_in[(size_t)(j0 + jr) * IN_D + kb * 32 + c0 + qd * 4];
                wsh[jr][c0 + qd * 4]     = v.x; wsh[jr][c0 + qd * 4 + 1] = v.y;
                wsh[jr][c0 + qd * 4 + 2] = v.z; wsh[jr][c0 + qd * 4 + 3] = v.w;
            }
        }
        __syncthreads();
#pragma unroll 4
        for (int k = 0; k < 32; ++k) {
            float xv[4], wv[8];
#pragma unroll
            for (int ii = 0; ii < 4; ++ii) xv[ii] = xs[ti * 4 + ii][k];
#pragma unroll
            for (int jj = 0; jj < 8; ++jj) wv[jj] = wsh[tj + 32 * jj][k];
#pragma unroll
            for (int ii = 0; ii < 4; ++ii)
#pragma unroll
                for (int jj = 0; jj < 8; ++jj)
                    acc[ii][jj] = fmaf(xv[ii], wv[jj], acc[ii][jj]);
        }
    }
#pragma unroll
    for (int ii = 0; ii < 4; ++ii)
#pragma unroll
        for (int jj = 0; jj < 8; ++jj) {
            int ig = i0 + ti * 4 + ii, jg = j0 + tj + 32 * jj;
            float r = acc[ii][jj] + b_in[jg] + b_h[jg];
            if (preF32) pre32[(size_t)ig * HID + jg] = r;
            else        pre16[(size_t)ig * HID + jg] = __builtin_bit_cast(uint16_t, (f16)r);
        }
}

// ---------------------------------------------------------------------------
// K2: sequential scan. 512 threads (8 waves, 2/SIMD). Thread t: rows
// rg*8..rg*8+7 (rg=t>>3) over k slice [kg*64, kg*64+64) (kg=t&7).
// 7-shfl payload-halving reduce leaves lane owning row t exactly.
// ---------------------------------------------------------------------------
__global__ __launch_bounds__(NT, 2) void k_scan(
    const uint32_t* __restrict__ ode_prep, const uint32_t* __restrict__ wh_prep,
    const float* __restrict__ pre32, const uint16_t* __restrict__ pre16, int preF32,
    const float* __restrict__ tarr, const float* __restrict__ b_ode,
    const float* __restrict__ W_dec, const float* __restrict__ b_dec,
    float* __restrict__ out)
{
    __shared__ uint4 wlds4[18 * NT];                  // 147456 B, lane-contiguous
    __shared__ __align__(16) uint16_t vbuf[2][576];   // f16 v, kg-stride 144B (9x16B)
    __shared__ float hbuf[HID];

    const int t  = threadIdx.x;
    const int kg = t & 7;
    const uint4* ode4 = (const uint4*)ode_prep;
    const uint4* wh4  = (const uint4*)wh_prep;

    uint32_t wreg[176];
#pragma unroll
    for (int j = 0; j < 44; ++j) {
        uint4 w = ode4[j * NT + t];
        wreg[4 * j] = w.x; wreg[4 * j + 1] = w.y;
        wreg[4 * j + 2] = w.z; wreg[4 * j + 3] = w.w;
    }
#pragma unroll
    for (int c = 0; c < 18; ++c)
        wlds4[c * NT + t] = ode4[(44 + c) * NT + t];

    const float bo = b_ode[t];
    __syncthreads();

    int cur = 1;
    auto push1 = [&](float val) {   // thread t publishes v[t]
        int nxt = cur ^ 1;
        vbuf[nxt][(t >> 6) * 72 + (t & 63)] = __builtin_bit_cast(uint16_t, (f16)val);
        __syncthreads();
        cur = nxt;
    };

    // payload-halving butterfly over kg (masks 1,2,4): lane ends with row t.
    auto reduce8 = [&](float acc[8]) -> float {
        const bool o1 = kg & 1, o2 = (kg >> 1) & 1, o4 = (kg >> 2) & 1;
        float b[4];
#pragma unroll
        for (int j = 0; j < 4; ++j) {
            float got = __shfl_xor(o1 ? acc[2 * j] : acc[2 * j + 1], 1);
            b[j] = (o1 ? acc[2 * j + 1] : acc[2 * j]) + got;
        }
        float c[2];
#pragma unroll
        for (int i2 = 0; i2 < 2; ++i2) {
            float got = __shfl_xor(o2 ? b[2 * i2] : b[2 * i2 + 1], 2);
            c[i2] = (o2 ? b[2 * i2 + 1] : b[2 * i2]) + got;
        }
        float got = __shfl_xor(o4 ? c[0] : c[1], 4);
        return (o4 ? c[1] : c[0]) + got;
    };

    // z = (W_ode v)[t]
    auto mv_ode = [&]() -> float {
        float acc[8] = {0.f, 0.f, 0.f, 0.f, 0.f, 0.f, 0.f, 0.f};
        uint4 st0 = ode4[62 * NT + t];   // L1-resident stream (rl7, c8=6)
        uint4 st1 = ode4[63 * NT + t];   // (rl7, c8=7)
        const char* vb = (const char*)&vbuf[cur][0] + kg * 144;
#pragma unroll
        for (int c8 = 0; c8 < 8; ++c8) {
            const uint4 vv = *(const uint4*)(vb + c8 * 16);
            uint4 w5, w7;
            if (c8 >= 4) w5 = wlds4[(c8 - 4) * NT + t];
            const uint4 w6 = wlds4[(4 + c8) * NT + t];
            if (c8 < 6) w7 = wlds4[(12 + c8) * NT + t];
#pragma unroll
            for (int mm = 0; mm < 4; ++mm) {
                const uint32_t vd = pick(vv, mm);
                acc[0] = dot2f(wreg[c8 * 4 + mm],       vd, acc[0]);
                acc[1] = dot2f(wreg[32 + c8 * 4 + mm],  vd, acc[1]);
                acc[2] = dot2f(wreg[64 + c8 * 4 + mm],  vd, acc[2]);
                acc[3] = dot2f(wreg[96 + c8 * 4 + mm],  vd, acc[3]);
                acc[4] = dot2f(wreg[128 + c8 * 4 + mm], vd, acc[4]);
                acc[5] = dot2f(c8 < 4 ? wreg[160 + c8 * 4 + mm] : pick(w5, mm), vd, acc[5]);
                acc[6] = dot2f(pick(w6, mm), vd, acc[6]);
                acc[7] = dot2f(c8 < 6 ? pick(w7, mm) : (c8 == 6 ? pick(st0, mm) : pick(st1, mm)),
                               vd, acc[7]);
            }
        }
        return reduce8(acc);
    };

    // z = (W_h v)[t]; W_h streamed from L2, 8-uint4 rolling prefetch (4 ahead)
    auto mv_wh = [&]() -> float {
        float acc[8] = {0.f, 0.f, 0.f, 0.f, 0.f, 0.f, 0.f, 0.f};
        const char* vb = (const char*)&vbuf[cur][0] + kg * 144;
        uint4 ru[8];
#pragma unroll
        for (int s = 0; s < 4; ++s) {            // sigma=0..3: p=0, c8=s
            ru[2 * s]     = wh4[s * NT + t];
            ru[2 * s + 1] = wh4[(s + 8) * NT + t];
        }
#pragma unroll
        for (int sig = 0; sig < 32; ++sig) {
            const int p = sig >> 3, c8 = sig & 7;
            const uint4 a = ru[2 * (sig & 3)];
            const uint4 b = ru[2 * (sig & 3) + 1];
            if (sig + 4 < 32) {
                const int s2 = sig + 4, jl = (s2 >> 3) * 16 + (s2 & 7);
                ru[2 * (sig & 3)]     = wh4[jl * NT + t];
                ru[2 * (sig & 3) + 1] = wh4[(jl + 8) * NT + t];
            }
            const uint4 vv = *(const uint4*)(vb + c8 * 16);
#pragma unroll
            for (int mm = 0; mm < 4; ++mm) {
                const uint32_t vd = pick(vv, mm);
                acc[2 * p]     = dot2f(pick(a, mm), vd, acc[2 * p]);
                acc[2 * p + 1] = dot2f(pick(b, mm), vd, acc[2 * p + 1]);
            }
        }
        return reduce8(acc);
    };

    // h0 = tanh(pre[0][t])
    float h;
    {
        float p0 = preF32 ? pre32[t] : (float)__builtin_bit_cast(f16, pre16[t]);
        h = fast_tanh(p0);
    }
    push1(h);
    float tprev = tarr[0];

#pragma unroll 1
    for (int i = 1; i < T_LEN; ++i) {
        float tc  = tarr[i];
        float dtt = tc - tprev; tprev = tc;
        float dt  = 0.25f * dtt;            // N_SUB = 4
        float hdt = 0.5f * dt;
        float sixth = dt * (1.f / 6.f);
        float pv = preF32 ? pre32[(size_t)i * HID + t]
                          : (float)__builtin_bit_cast(f16, pre16[(size_t)i * HID + t]);
#pragma unroll 1
        for (int sub = 0; sub < 4; ++sub) {
            float ks = 0.f;
#pragma unroll 1
            for (int s = 0; s < 4; ++s) {
                float z = mv_ode();
                float k = fast_tanh(z + bo);
                float wk = (s == 1 || s == 2) ? 2.f : 1.f;
                ks = fmaf(wk, k, ks);
                float n;
                if (s == 3) { h = fmaf(sixth, ks, h); n = h; }
                else        { float a = (s == 2) ? dt : hdt; n = fmaf(a, k, h); }
                push1(n);
            }
        }
        float zh = mv_wh();
        h = fast_tanh(pv + zh);
        push1(h);
    }

    // decode: out = W_dec @ h + b_dec
    hbuf[t] = h;
    __syncthreads();
    if (t < OUT_D) {
        float a = b_dec[t];
#pragma unroll 4
        for (int r4 = 0; r4 < 128; ++r4) {
            float4 w = *(const float4*)&W_dec[t * HID + r4 * 4];
            a = fmaf(w.x, hbuf[r4 * 4],     a);
            a = fmaf(w.y, hbuf[r4 * 4 + 1], a);
            a = fmaf(w.z, hbuf[r4 * 4 + 2], a);
            a = fmaf(w.w, hbuf[r4 * 4 + 3], a);
        }
        out[t] = a;
    }
}

// ---------------------------------------------------------------------------
extern "C" void kernel_launch(void* const* d_in, const int* in_sizes, int n_in,
                              void* d_out, int out_size, void* d_ws, size_t ws_size,
                              hipStream_t stream) {
    const float* tarr  = (const float*)d_in[0];
    const float* x     = (const float*)d_in[1];
    const float* W_in  = (const float*)d_in[2];
    const float* b_in  = (const float*)d_in[3];
    const float* W_h   = (const float*)d_in[4];
    const float* b_h   = (const float*)d_in[5];
    const float* W_ode = (const float*)d_in[6];
    const float* b_ode = (const float*)d_in[7];
    const float* W_dec = (const float*)d_in[8];
    const float* b_dec = (const float*)d_in[9];
    float* out = (float*)d_out;

    uint8_t*  ws       = (uint8_t*)d_ws;
    uint32_t* ode_prep = (uint32_t*)(ws);                  // 512 KB
    uint32_t* wh_prep  = (uint32_t*)(ws + (512u << 10));   // 512 KB
    void*     pre      = (void*)(ws + (1u << 20));         // 64 MB f32 or 32 MB f16

    size_t need32 = (1u << 20) + (size_t)T_LEN * HID * 4 + 4096;
    int preF32 = (ws_size >= need32) ? 1 : 0;

    hipLaunchKernelGGL(k_prep, dim3(2), dim3(NT), 0, stream, W_ode, W_h, ode_prep, wh_prep);
    hipLaunchKernelGGL(k_pre,  dim3(1024), dim3(512), 0, stream, x, W_in, b_in, b_h,
                       (float*)pre, (uint16_t*)pre, preF32);
    hipLaunchKernelGGL(k_scan, dim3(1), dim3(NT), 0, stream, ode_prep, wh_prep,
                       (const float*)pre, (const uint16_t*)pre, preF32,
                       tarr, b_ode, W_dec, b_dec, out);
}